// Round 3
// baseline (12111.132 us; speedup 1.0000x reference)
//
#include <hip/hip_runtime.h>

// ---------------------------------------------------------------------------
// HeteroSimplexLayer on MI355X (gfx950).
// Algebra: W_comb[r] = tri_W[r] @ node_W[r]; scatter mean_x first, GEMM after.
// Attention split: qk -> 4x4 softmax weights A -> v -> combine.
// Node-chunked pipeline, chunk size adapted to ws_size at launch.
// ---------------------------------------------------------------------------

#define NNODES 100000
#define NPAD   100096          // 782 tiles of 128
#define DIM    256
#define NREL   4
#define NTRI   150000

typedef unsigned short ushortT;
typedef __attribute__((ext_vector_type(8)))  short   short8;
typedef __attribute__((ext_vector_type(4)))  float   floatx4;
typedef __attribute__((ext_vector_type(4)))  unsigned short ushort4v;

__device__ __forceinline__ float bf2f(ushortT u) {
    union { unsigned int i; float f; } c; c.i = ((unsigned int)u) << 16; return c.f;
}
__device__ __forceinline__ ushortT f2bf(float f) {
    union { float f; unsigned int i; } c; c.f = f;
    unsigned int x = c.i;
    x += 0x7fffu + ((x >> 16) & 1u);      // RNE
    return (ushortT)(x >> 16);
}

// -------------------------------- small kernels ----------------------------

__global__ void cvt_f32_bf16(const float* __restrict__ in, ushortT* __restrict__ out, int n4) {
    int i = blockIdx.x * blockDim.x + threadIdx.x;
    int stride = gridDim.x * blockDim.x;
    for (; i < n4; i += stride) {
        float4 v = ((const float4*)in)[i];
        ushort4v o; o.x = f2bf(v.x); o.y = f2bf(v.y); o.z = f2bf(v.z); o.w = f2bf(v.w);
        ((ushort4v*)out)[i] = o;
    }
}

// W_comb[r][o][k] = sum_j tri_W[r][o][j] * node_W[r][j][k]
__global__ void wcomb_kernel(const float* __restrict__ nodeW, const float* __restrict__ triW,
                             ushortT* __restrict__ wcomb) {
    int idx = blockIdx.x * 256 + threadIdx.x;       // r*65536 + o*256 + k
    int r = idx >> 16, o = (idx >> 8) & 255, k = idx & 255;
    const float* tw = triW  + ((size_t)r << 16) + o * 256;
    const float* nw = nodeW + ((size_t)r << 16) + k;
    float s = 0.f;
    #pragma unroll 8
    for (int j = 0; j < 256; ++j) s += tw[j] * nw[(size_t)j * 256];
    wcomb[idx] = f2bf(s);
}

__global__ void scatter_cnt(const int* __restrict__ tri, float* __restrict__ cnt, int n) {
    int i = blockIdx.x * 256 + threadIdx.x;
    if (i < n) atomicAdd(&cnt[tri[i]], 1.0f);
}

// per triangle: v = (x[a]+x[b]+x[c])/3 ; atomically add v to acc rows a,b,c
__global__ __launch_bounds__(256) void scatter_add(const int* __restrict__ tri,
                                                   const float* __restrict__ x,
                                                   float* __restrict__ acc, int T) {
    int t = blockIdx.x * 4 + (threadIdx.x >> 6);
    if (t >= T) return;
    int lane = threadIdx.x & 63;
    int a = tri[t], b = tri[T + t], c = tri[2 * T + t];
    const float4 va = ((const float4*)(x + (size_t)a * DIM))[lane];
    const float4 vb = ((const float4*)(x + (size_t)b * DIM))[lane];
    const float4 vc = ((const float4*)(x + (size_t)c * DIM))[lane];
    float4 v; v.x = (va.x + vb.x + vc.x) * (1.0f / 3.0f);
    v.y = (va.y + vb.y + vc.y) * (1.0f / 3.0f);
    v.z = (va.z + vb.z + vc.z) * (1.0f / 3.0f);
    v.w = (va.w + vb.w + vc.w) * (1.0f / 3.0f);
    float* pa = acc + (size_t)a * DIM + lane * 4;
    float* pb = acc + (size_t)b * DIM + lane * 4;
    float* pc = acc + (size_t)c * DIM + lane * 4;
    atomicAdd(pa + 0, v.x); atomicAdd(pa + 1, v.y); atomicAdd(pa + 2, v.z); atomicAdd(pa + 3, v.w);
    atomicAdd(pb + 0, v.x); atomicAdd(pb + 1, v.y); atomicAdd(pb + 2, v.z); atomicAdd(pb + 3, v.w);
    atomicAdd(pc + 0, v.x); atomicAdd(pc + 1, v.y); atomicAdd(pc + 2, v.z); atomicAdd(pc + 3, v.w);
}

// -------------------------------- GEMM -------------------------------------
// C[m, col] = sum_k A[m,k] * W[col,k]. 128x128 tile, BK=32, 4 waves (2x2),
// each wave 64x64 via 4x4 MFMA 16x16x32 bf16. m97-verified structure.

#define BM 128
#define BN 128
#define BK 32

__device__ __forceinline__ void async_cp16(char* lds, const char* glb) {
    __builtin_amdgcn_global_load_lds((const __attribute__((address_space(1))) unsigned int*)glb,
                                     (__attribute__((address_space(3))) unsigned int*)lds,
                                     16, 0, 0);
}

enum { M_F32 = 0, M_NODEMSG = 1, M_GATE = 2, M_QKV = 3, M_RES = 4, M_GELU = 5 };

template <int MODE>
__global__ __launch_bounds__(256)
void gemm_bt(const ushortT* __restrict__ A, int lda,
             const ushortT* __restrict__ W, int ldw,
             int M, int K,
             float* __restrict__ outF, ushortT* __restrict__ outB, int ldo,
             const float* __restrict__ bias,
             const float* __restrict__ cnt,
             const float* __restrict__ gx,
             const float* __restrict__ xres,
             const ushortT* __restrict__ ub,
             const ushortT* __restrict__ resb) {
    __shared__ __align__(16) ushortT As[BM * BK];
    __shared__ __align__(16) ushortT Bs[BN * BK];
    const int tid  = threadIdx.x;
    const int wave = tid >> 6, lane = tid & 63;
    const int m0 = blockIdx.y * BM;
    const int n0 = blockIdx.x * BN;
    const int wm = (wave >> 1) * 64, wn = (wave & 1) * 64;

    floatx4 acc[4][4];
    #pragma unroll
    for (int i = 0; i < 4; ++i)
        #pragma unroll
        for (int j = 0; j < 4; ++j) acc[i][j] = (floatx4){0.f, 0.f, 0.f, 0.f};

    const int r4  = tid >> 2;            // row within 64-row chunk
    const int b16 = (tid & 3) * 16;      // byte offset in 64B row slice
    const char* Ab = (const char*)A + ((size_t)(m0 + r4) * lda) * 2 + b16;
    const char* Wb = (const char*)W + ((size_t)(n0 + r4) * ldw) * 2 + b16;
    char* Asl = (char*)As + wave * 1024; // wave-uniform LDS base
    char* Bsl = (char*)Bs + wave * 1024;

    for (int k0 = 0; k0 < K; k0 += BK) {
        async_cp16(Asl,        Ab + k0 * 2);
        async_cp16(Asl + 4096, Ab + k0 * 2 + (size_t)64 * lda * 2);
        async_cp16(Bsl,        Wb + k0 * 2);
        async_cp16(Bsl + 4096, Wb + k0 * 2 + (size_t)64 * ldw * 2);
        __syncthreads();
        const int kq = (lane >> 4) * 8;
        const int ra = wm + (lane & 15);
        const int rb = wn + (lane & 15);
        short8 af[4], bfr[4];
        #pragma unroll
        for (int i = 0; i < 4; ++i) {
            af[i]  = *(const short8*)(As + (ra + i * 16) * BK + kq);
            bfr[i] = *(const short8*)(Bs + (rb + i * 16) * BK + kq);
        }
        #pragma unroll
        for (int mi = 0; mi < 4; ++mi)
            #pragma unroll
            for (int ni = 0; ni < 4; ++ni)
                acc[mi][ni] = __builtin_amdgcn_mfma_f32_16x16x32_bf16(af[mi], bfr[ni], acc[mi][ni], 0, 0, 0);
        __syncthreads();
    }

    const int cl = lane & 15, rw = (lane >> 4) * 4;
    #pragma unroll
    for (int mi = 0; mi < 4; ++mi) {
        #pragma unroll
        for (int e = 0; e < 4; ++e) {
            const int m = m0 + wm + mi * 16 + rw + e;
            if (m >= M) continue;
            #pragma unroll
            for (int ni = 0; ni < 4; ++ni) {
                const int col = n0 + wn + ni * 16 + cl;
                float c = acc[mi][ni][e];
                if (MODE == M_F32) {
                    outF[(size_t)m * ldo + col] = c;
                } else if (MODE == M_NODEMSG) {
                    c /= fmaxf(cnt[m], 1.0f);
                    c = c > 0.f ? c : (expf(c) - 1.0f);          // elu
                    outB[(size_t)m * ldo + col] = f2bf(c);
                } else if (MODE == M_GATE) {
                    float a  = 1.0f / (1.0f + expf(-(c + gx[(size_t)m * 256 + col] + bias[col])));
                    float uv = bf2f(ub[(size_t)m * 256 + col]);
                    float h  = tanhf(uv) * a + xres[(size_t)m * 256 + col] * (1.0f - a);
                    outB[(size_t)m * ldo + col] = f2bf(h);
                } else if (MODE == M_QKV) {
                    outB[(size_t)m * ldo + col] = f2bf(c + bias[col]);
                } else if (MODE == M_RES) {
                    outF[(size_t)m * ldo + col] = c + bias[col] + bf2f(resb[(size_t)m * 256 + col]);
                } else if (MODE == M_GELU) {
                    float t = c + bias[col];
                    outB[(size_t)m * ldo + col] = f2bf(0.5f * t * (1.0f + erff(t * 0.70710678118f)));
                }
            }
        }
    }
}

// ------------------------------ attention ----------------------------------
// qk[r]: [Nc,512] bf16 (q cols 0..255, k cols 256..511). One wave per node;
// lanes 0..31 = head 0, 32..63 = head 1. Writes softmaxed A[n,2,4,4] f32.
__global__ __launch_bounds__(256)
void attn_score(const ushortT* __restrict__ qk, size_t rstride,
                float* __restrict__ Aw, int nvalid) {
    int n = blockIdx.x * 4 + (threadIdx.x >> 6);
    if (n >= nvalid) return;
    int lane = threadIdx.x & 63;
    int head = lane >> 5, hl = lane & 31;
    int d = head * 128 + hl * 4;
    float q[NREL][4], k[NREL][4];
    #pragma unroll
    for (int r = 0; r < NREL; ++r) {
        const ushortT* base = qk + r * rstride + (size_t)n * 512;
        ushort4v qv = *(const ushort4v*)(base + d);
        ushort4v kv = *(const ushort4v*)(base + 256 + d);
        q[r][0] = bf2f(qv.x); q[r][1] = bf2f(qv.y); q[r][2] = bf2f(qv.z); q[r][3] = bf2f(qv.w);
        k[r][0] = bf2f(kv.x); k[r][1] = bf2f(kv.y); k[r][2] = bf2f(kv.z); k[r][3] = bf2f(kv.w);
    }
    float s[NREL][NREL];
    #pragma unroll
    for (int qr = 0; qr < NREL; ++qr)
        #pragma unroll
        for (int kr = 0; kr < NREL; ++kr) {
            float p = q[qr][0] * k[kr][0] + q[qr][1] * k[kr][1] +
                      q[qr][2] * k[kr][2] + q[qr][3] * k[kr][3];
            #pragma unroll
            for (int off = 1; off < 32; off <<= 1) p += __shfl_xor(p, off, 32);
            s[qr][kr] = p * 0.08838834764831845f;   // 1/sqrt(128)
        }
    if (hl < 16) {
        int qr = hl >> 2, kr = hl & 3;
        float mx = fmaxf(fmaxf(s[qr][0], s[qr][1]), fmaxf(s[qr][2], s[qr][3]));
        float e0 = expf(s[qr][0] - mx), e1 = expf(s[qr][1] - mx);
        float e2 = expf(s[qr][2] - mx), e3 = expf(s[qr][3] - mx);
        float e  = expf(s[qr][kr] - mx);
        Aw[((size_t)n * 2 + head) * 16 + qr * 4 + kr] = e / (e0 + e1 + e2 + e3);
    }
}

// o[qr,n,:] = sum_kr A[n,head,qr,kr] * v[kr,n,:]
__global__ __launch_bounds__(256)
void attn_combine(const ushortT* __restrict__ v4, size_t rstride,
                  const float* __restrict__ Aw, ushortT* __restrict__ o4, int nvalid) {
    int n = blockIdx.x * 4 + (threadIdx.x >> 6);
    if (n >= nvalid) return;
    int lane = threadIdx.x & 63;
    int head = lane >> 5, d4 = lane * 4;
    float a[NREL][NREL];
    const float* ap = Aw + ((size_t)n * 2 + head) * 16;
    #pragma unroll
    for (int qr = 0; qr < NREL; ++qr)
        #pragma unroll
        for (int kr = 0; kr < NREL; ++kr) a[qr][kr] = ap[qr * 4 + kr];
    float vv[NREL][4];
    #pragma unroll
    for (int r = 0; r < NREL; ++r) {
        ushort4v t = *(const ushort4v*)(v4 + r * rstride + (size_t)n * 256 + d4);
        vv[r][0] = bf2f(t.x); vv[r][1] = bf2f(t.y); vv[r][2] = bf2f(t.z); vv[r][3] = bf2f(t.w);
    }
    #pragma unroll
    for (int qr = 0; qr < NREL; ++qr) {
        ushort4v o;
        o.x = f2bf(a[qr][0] * vv[0][0] + a[qr][1] * vv[1][0] + a[qr][2] * vv[2][0] + a[qr][3] * vv[3][0]);
        o.y = f2bf(a[qr][0] * vv[0][1] + a[qr][1] * vv[1][1] + a[qr][2] * vv[2][1] + a[qr][3] * vv[3][1]);
        o.z = f2bf(a[qr][0] * vv[0][2] + a[qr][1] * vv[1][2] + a[qr][2] * vv[2][2] + a[qr][3] * vv[3][2]);
        o.w = f2bf(a[qr][0] * vv[0][3] + a[qr][1] * vv[1][3] + a[qr][2] * vv[2][3] + a[qr][3] * vv[3][3]);
        *(ushort4v*)(o4 + qr * rstride + (size_t)n * 256 + d4) = o;
    }
}

// ------------------------------ layernorm ----------------------------------
// mode 0: write bf16 row.  mode 1: outacc[row] += 0.25 * LN(row)
__global__ __launch_bounds__(256)
void ln_rows(const float* __restrict__ z, const float* __restrict__ g, const float* __restrict__ b,
             ushortT* __restrict__ outb, float* __restrict__ outacc, int n, int mode) {
    int row = blockIdx.x * 4 + (threadIdx.x >> 6);
    if (row >= n) return;
    int lane = threadIdx.x & 63;
    const float4 v = *(const float4*)(z + (size_t)row * 256 + lane * 4);
    float s = v.x + v.y + v.z + v.w;
    #pragma unroll
    for (int off = 1; off < 64; off <<= 1) s += __shfl_xor(s, off, 64);
    float mean = s * (1.0f / 256.0f);
    float dx = v.x - mean, dy = v.y - mean, dz = v.z - mean, dw = v.w - mean;
    float qs = dx * dx + dy * dy + dz * dz + dw * dw;
    #pragma unroll
    for (int off = 1; off < 64; off <<= 1) qs += __shfl_xor(qs, off, 64);
    float rstd = rsqrtf(qs * (1.0f / 256.0f) + 1e-5f);
    int c0 = lane * 4;
    float y0 = dx * rstd * g[c0 + 0] + b[c0 + 0];
    float y1 = dy * rstd * g[c0 + 1] + b[c0 + 1];
    float y2 = dz * rstd * g[c0 + 2] + b[c0 + 2];
    float y3 = dw * rstd * g[c0 + 3] + b[c0 + 3];
    if (mode == 0) {
        ushort4v o; o.x = f2bf(y0); o.y = f2bf(y1); o.z = f2bf(y2); o.w = f2bf(y3);
        *(ushort4v*)(outb + (size_t)row * 256 + c0) = o;
    } else {
        float4* p = (float4*)(outacc + (size_t)row * 256 + c0);
        float4 cur = *p;
        cur.x += 0.25f * y0; cur.y += 0.25f * y1; cur.z += 0.25f * y2; cur.w += 0.25f * y3;
        *p = cur;
    }
}

// ------------------------------ host ---------------------------------------

extern "C" void kernel_launch(void* const* d_in, const int* in_sizes, int n_in,
                              void* d_out, int out_size, void* d_ws, size_t ws_size,
                              hipStream_t stream) {
    const float* x      = (const float*)d_in[0];
    const int*   tri    = (const int*)d_in[1];
    const float* nodeW  = (const float*)d_in[3];
    const float* triW   = (const float*)d_in[4];
    const float* resW   = (const float*)d_in[5];
    const float* gateW  = (const float*)d_in[6];
    const float* gate_b = (const float*)d_in[7];
    const float* inW    = (const float*)d_in[8];
    const float* in_b   = (const float*)d_in[9];
    const float* outW   = (const float*)d_in[10];
    const float* out_b  = (const float*)d_in[11];
    const float* ln1g   = (const float*)d_in[12];
    const float* ln1b   = (const float*)d_in[13];
    const float* lin1W  = (const float*)d_in[14];
    const float* lin1b  = (const float*)d_in[15];
    const float* lin2W  = (const float*)d_in[16];
    const float* lin2b  = (const float*)d_in[17];
    const float* ln2g   = (const float*)d_in[18];
    const float* ln2b   = (const float*)d_in[19];
    float* out = (float*)d_out;

    // ---------------- persistent workspace layout ----------------
    char* ws = (char*)d_ws;
    size_t off = 0;
    auto alloc = [&](size_t bytes) -> char* {
        char* p = ws + off; off += (bytes + 255) & ~(size_t)255; return p;
    };
    ushortT* accAll  = (ushortT*)alloc((size_t)NREL * NPAD * 256 * 2);  // 205 MB
    float*   cntAll  = (float*)  alloc((size_t)NREL * NPAD * 4);        // 1.6 MB
    ushortT* wcomb   = (ushortT*)alloc((size_t)NREL * 65536 * 2);
    ushortT* resW_b  = (ushortT*)alloc((size_t)65536 * 2);
    ushortT* gateW_b = (ushortT*)alloc((size_t)131072 * 2);
    ushortT* inW_b   = (ushortT*)alloc((size_t)196608 * 2);
    ushortT* outW_b  = (ushortT*)alloc((size_t)65536 * 2);
    ushortT* lin1_bf = (ushortT*)alloc((size_t)131072 * 2);
    ushortT* lin2_bf = (ushortT*)alloc((size_t)131072 * 2);
    size_t persist = off;
    size_t scratch = (ws_size > persist) ? (ws_size - persist) : 0;

    // scatter needs a full-N f32 accumulator in scratch
    if (scratch < (size_t)NPAD * 1024) return;
    // pick tiles-per-chunk: per-row scratch = 9344 B
    int TT = (NNODES + 127) / 128;              // 782
    int tpc = TT;
    while ((size_t)9344 * tpc * 128 > scratch && tpc > 1) tpc = (tpc + 1) / 2;
    if ((size_t)9344 * tpc * 128 > scratch) return;
    const size_t NcPad = (size_t)tpc * 128;
    const int nchunks = (TT + tpc - 1) / tpc;

    char* S = ws + persist;
    // chunk scratch layout (bytes/row), with phase aliasing:
    ushortT* xbf   = (ushortT*)(S);                    // 512
    float*   xres  = (float*)  (S + 512  * NcPad);     // 1024
    float*   Gx    = (float*)  (S + 1536 * NcPad);     // 1024
    ushortT* ubf   = (ushortT*)(S + 2560 * NcPad);     // 512
    float*   zb    = (float*)  (S);                    // phase-B alias: 1024
    ushortT* x1    = (ushortT*)(S + 1024 * NcPad);     // phase-B alias: 512
    ushortT* ffg   = (ushortT*)(S + 1536 * NcPad);     // phase-B alias: 1024
    ushortT* h4    = (ushortT*)(S + 3072 * NcPad);     // 4 x 512
    ushortT* qk4   = (ushortT*)(S + 5120 * NcPad);     // 4 x 1024
    ushortT* v4    = (ushortT*)(S + 5120 * NcPad);     // alias (qk dead)
    ushortT* o4    = (ushortT*)(S + 7168 * NcPad);     // alias (qk dead)
    float*   Aw    = (float*)  (S + 9216 * NcPad);     // 128
    float*   zscat = (float*)  (S);                    // scatter phase (full N)

    (void)hipMemsetAsync(d_out, 0, (size_t)out_size * 4, stream);

    // ---------------- weights to bf16 + W_comb ----------------
    cvt_f32_bf16<<<64, 256, 0, stream>>>(resW,  resW_b,  65536 / 4);
    cvt_f32_bf16<<<64, 256, 0, stream>>>(gateW, gateW_b, 131072 / 4);
    cvt_f32_bf16<<<64, 256, 0, stream>>>(inW,   inW_b,   196608 / 4);
    cvt_f32_bf16<<<64, 256, 0, stream>>>(outW,  outW_b,  65536 / 4);
    cvt_f32_bf16<<<64, 256, 0, stream>>>(lin1W, lin1_bf, 131072 / 4);
    cvt_f32_bf16<<<64, 256, 0, stream>>>(lin2W, lin2_bf, 131072 / 4);
    wcomb_kernel<<<1024, 256, 0, stream>>>(nodeW, triW, wcomb);

    // ---------------- scatter phase (full N, per relation) ----------------
    (void)hipMemsetAsync(cntAll, 0, (size_t)NREL * NPAD * 4, stream);
    for (int r = 0; r < NREL; ++r) {
        (void)hipMemsetAsync(zscat, 0, (size_t)NPAD * 1024, stream);
        const int* trir = tri + (size_t)r * 3 * NTRI;
        scatter_cnt<<<(3 * NTRI + 255) / 256, 256, 0, stream>>>(trir, cntAll + (size_t)r * NPAD, 3 * NTRI);
        scatter_add<<<(NTRI + 3) / 4, 256, 0, stream>>>(trir, x, zscat, NTRI);
        cvt_f32_bf16<<<2048, 256, 0, stream>>>(zscat, accAll + (size_t)r * NPAD * 256, NNODES * 64);
    }

    // ---------------- chunked main pipeline ----------------
    for (int ci = 0; ci < nchunks; ++ci) {
        const int rows0 = ci * tpc * 128;
        int mact = NNODES - rows0;
        if (mact <= 0) break;
        if (mact > tpc * 128) mact = tpc * 128;
        const int tiles = (mact + 127) / 128;
        const dim3 g2(2, tiles), g4(4, tiles);
        const int nwblk = (mact + 3) / 4;
        float* outc = out + (size_t)rows0 * 256;

        cvt_f32_bf16<<<2048, 256, 0, stream>>>(x + (size_t)rows0 * 256, xbf, mact * 64);
        // xres = x @ res_W.T ; Gx = x @ gate_W[:, :D].T
        gemm_bt<M_F32><<<g2, 256, 0, stream>>>(xbf, 256, resW_b, 256, mact, 256,
            xres, nullptr, 256, nullptr, nullptr, nullptr, nullptr, nullptr, nullptr);
        gemm_bt<M_F32><<<g2, 256, 0, stream>>>(xbf, 256, gateW_b, 512, mact, 256,
            Gx, nullptr, 256, nullptr, nullptr, nullptr, nullptr, nullptr, nullptr);

        for (int r = 0; r < NREL; ++r) {
            // u = elu((acc @ W_comb.T) / cnt)
            gemm_bt<M_NODEMSG><<<g2, 256, 0, stream>>>(
                accAll + ((size_t)r * NPAD + rows0) * 256, 256, wcomb + (size_t)r * 65536, 256,
                mact, 256, nullptr, ubf, 256, nullptr,
                cntAll + (size_t)r * NPAD + rows0, nullptr, nullptr, nullptr, nullptr);
            // a = sigmoid(Gx + u@gW2.T + b); h = tanh(u)*a + xres*(1-a)
            gemm_bt<M_GATE><<<g2, 256, 0, stream>>>(ubf, 256, gateW_b + 256, 512, mact, 256,
                nullptr, h4 + (size_t)r * 256 * NcPad, 256, gate_b, nullptr, Gx, xres, ubf, nullptr);
        }
        for (int r = 0; r < NREL; ++r)   // qk = h @ in_W[0:512].T + b
            gemm_bt<M_QKV><<<g4, 256, 0, stream>>>(h4 + (size_t)r * 256 * NcPad, 256, inW_b, 256,
                mact, 256, nullptr, qk4 + (size_t)r * 512 * NcPad, 512, in_b,
                nullptr, nullptr, nullptr, nullptr, nullptr);
        attn_score<<<nwblk, 256, 0, stream>>>(qk4, 512 * NcPad, Aw, mact);
        for (int r = 0; r < NREL; ++r)   // v = h @ in_W[512:768].T + b  (qk region dead)
            gemm_bt<M_QKV><<<g2, 256, 0, stream>>>(h4 + (size_t)r * 256 * NcPad, 256,
                inW_b + 512 * 256, 256, mact, 256, nullptr, v4 + (size_t)r * 256 * NcPad, 256,
                in_b + 512, nullptr, nullptr, nullptr, nullptr, nullptr);
        attn_combine<<<nwblk, 256, 0, stream>>>(v4, 256 * NcPad, Aw, o4, mact);

        for (int r = 0; r < NREL; ++r) {
            // z = h + o@out_W.T + out_b ; x1 = LN1(z)
            gemm_bt<M_RES><<<g2, 256, 0, stream>>>(o4 + (size_t)r * 256 * NcPad, 256, outW_b, 256,
                mact, 256, zb, nullptr, 256, out_b, nullptr, nullptr, nullptr, nullptr,
                h4 + (size_t)r * 256 * NcPad);
            ln_rows<<<nwblk, 256, 0, stream>>>(zb, ln1g, ln1b, x1, nullptr, mact, 0);
            // ffg = gelu(x1 @ lin1_W.T + b)
            gemm_bt<M_GELU><<<g4, 256, 0, stream>>>(x1, 256, lin1_bf, 256, mact, 256,
                nullptr, ffg, 512, lin1b, nullptr, nullptr, nullptr, nullptr, nullptr);
            // z = x1 + ffg @ lin2_W.T + b ; out += 0.25 * LN2(z)
            gemm_bt<M_RES><<<g2, 256, 0, stream>>>(ffg, 512, lin2_bf, 512, mact, 512,
                zb, nullptr, 256, lin2b, nullptr, nullptr, nullptr, nullptr, x1);
            ln_rows<<<nwblk, 256, 0, stream>>>(zb, ln2g, ln2b, nullptr, outc, mact, 1);
        }
    }
}

// Round 4
// 5146.539 us; speedup vs baseline: 2.3533x; 2.3533x over previous
//
#include <hip/hip_runtime.h>

// ---------------------------------------------------------------------------
// HeteroSimplexLayer on MI355X (gfx950).
// Algebra: W_comb[r] = tri_W[r] @ node_W[r]; CSR gather of triangle means
// (atomic-free), /cnt folded before GEMM. Attention split q·k -> 4x4 softmax
// -> v -> combine. Node-chunked pipeline adapted to ws_size.
// ---------------------------------------------------------------------------

#define NNODES 100000
#define NPAD   100096          // 782 tiles of 128
#define DIM    256
#define NREL   4
#define NTRI   150000

typedef unsigned short ushortT;
typedef __attribute__((ext_vector_type(8)))  short   short8;
typedef __attribute__((ext_vector_type(4)))  float   floatx4;
typedef __attribute__((ext_vector_type(4)))  unsigned short ushort4v;

__device__ __forceinline__ float bf2f(ushortT u) {
    union { unsigned int i; float f; } c; c.i = ((unsigned int)u) << 16; return c.f;
}
__device__ __forceinline__ ushortT f2bf(float f) {
    union { float f; unsigned int i; } c; c.f = f;
    unsigned int x = c.i;
    x += 0x7fffu + ((x >> 16) & 1u);      // RNE
    return (ushortT)(x >> 16);
}

// -------------------------------- small kernels ----------------------------

__global__ void cvt_f32_bf16(const float* __restrict__ in, ushortT* __restrict__ out, int n4) {
    int i = blockIdx.x * blockDim.x + threadIdx.x;
    int stride = gridDim.x * blockDim.x;
    for (; i < n4; i += stride) {
        float4 v = ((const float4*)in)[i];
        ushort4v o; o.x = f2bf(v.x); o.y = f2bf(v.y); o.z = f2bf(v.z); o.w = f2bf(v.w);
        ((ushort4v*)out)[i] = o;
    }
}

// W_comb[r][o][k] = sum_j tri_W[r][o][j] * node_W[r][j][k]
__global__ void wcomb_kernel(const float* __restrict__ nodeW, const float* __restrict__ triW,
                             ushortT* __restrict__ wcomb) {
    int idx = blockIdx.x * 256 + threadIdx.x;       // r*65536 + o*256 + k
    int r = idx >> 16, o = (idx >> 8) & 255, k = idx & 255;
    const float* tw = triW  + ((size_t)r << 16) + o * 256;
    const float* nw = nodeW + ((size_t)r << 16) + k;
    float s = 0.f;
    #pragma unroll 8
    for (int j = 0; j < 256; ++j) s += tw[j] * nw[(size_t)j * 256];
    wcomb[idx] = f2bf(s);
}

// ------------------------- CSR build (atomic-free gather) ------------------

__global__ void k_count(const int* __restrict__ tri3, int* __restrict__ cnt, int n3) {
    int i = blockIdx.x * 256 + threadIdx.x;
    if (i < n3) atomicAdd(&cnt[tri3[i]], 1);
}

__global__ void k_scan1(const int* __restrict__ cnt, int* __restrict__ ptr,
                        int* __restrict__ bsum, int n) {
    __shared__ int s[256];
    int i = blockIdx.x * 256 + threadIdx.x;
    int v = (i < n) ? cnt[i] : 0;
    s[threadIdx.x] = v; __syncthreads();
    for (int off = 1; off < 256; off <<= 1) {
        int t = (threadIdx.x >= off) ? s[threadIdx.x - off] : 0;
        __syncthreads();
        s[threadIdx.x] += t;
        __syncthreads();
    }
    if (i < n) ptr[i] = s[threadIdx.x] - v;            // block-local exclusive
    if (threadIdx.x == 255) bsum[blockIdx.x] = s[255];
}

__global__ void k_scan2(const int* __restrict__ bsum, int* __restrict__ bpre, int nb) {
    int lane = threadIdx.x & 63;
    int run = 0;
    for (int c = 0; c < nb; c += 64) {
        int idx = c + lane;
        int v = (idx < nb) ? bsum[idx] : 0;
        int incl = v;
        #pragma unroll
        for (int off = 1; off < 64; off <<= 1) {
            int t = __shfl_up(incl, off, 64);
            if (lane >= off) incl += t;
        }
        if (idx < nb) bpre[idx] = run + incl - v;
        run += __shfl(incl, 63, 64);
    }
}

__global__ void k_scan3(const int* __restrict__ bpre, int* __restrict__ ptr,
                        int* __restrict__ cursor, int n) {
    int i = blockIdx.x * 256 + threadIdx.x;
    if (i < n) { int p = ptr[i] + bpre[blockIdx.x]; ptr[i] = p; cursor[i] = p; }
}

__global__ void k_fill(const int* __restrict__ tri3, int* __restrict__ cursor,
                       int* __restrict__ adj, int n3, int T) {
    int i = blockIdx.x * 256 + threadIdx.x;
    if (i >= n3) return;
    int node = tri3[i];
    int t = i; if (t >= 2 * T) t -= 2 * T; else if (t >= T) t -= T;
    int pos = atomicAdd(&cursor[node], 1);
    adj[pos] = t;
}

// meanx[t] = (x[a]+x[b]+x[c])/3 as bf16 row
__global__ __launch_bounds__(256)
void k_meanx(const int* __restrict__ tri, const float* __restrict__ x,
             ushortT* __restrict__ mx, int T) {
    int t = blockIdx.x * 4 + (threadIdx.x >> 6);
    if (t >= T) return;
    int lane = threadIdx.x & 63;
    int a = tri[t], b = tri[T + t], c = tri[2 * T + t];
    const float4 va = ((const float4*)(x + (size_t)a * DIM))[lane];
    const float4 vb = ((const float4*)(x + (size_t)b * DIM))[lane];
    const float4 vc = ((const float4*)(x + (size_t)c * DIM))[lane];
    ushort4v o;
    o.x = f2bf((va.x + vb.x + vc.x) * (1.0f / 3.0f));
    o.y = f2bf((va.y + vb.y + vc.y) * (1.0f / 3.0f));
    o.z = f2bf((va.z + vb.z + vc.z) * (1.0f / 3.0f));
    o.w = f2bf((va.w + vb.w + vc.w) * (1.0f / 3.0f));
    *(ushort4v*)(mx + (size_t)t * DIM + lane * 4) = o;
}

// acc_bf[n] = (sum over incident triangles of meanx[t]) / max(cnt,1)
__global__ __launch_bounds__(256)
void k_gather(const int* __restrict__ ptr, const int* __restrict__ cnt,
              const int* __restrict__ adj, const ushortT* __restrict__ mx,
              ushortT* __restrict__ accb, int n) {
    int node = blockIdx.x * 4 + (threadIdx.x >> 6);
    if (node >= n) return;
    int lane = threadIdx.x & 63;
    int st = ptr[node], c = cnt[node];
    float a0 = 0.f, a1 = 0.f, a2 = 0.f, a3 = 0.f;
    for (int j = 0; j < c; ++j) {
        int t = adj[st + j];
        ushort4v v = *(const ushort4v*)(mx + (size_t)t * DIM + lane * 4);
        a0 += bf2f(v.x); a1 += bf2f(v.y); a2 += bf2f(v.z); a3 += bf2f(v.w);
    }
    float inv = 1.0f / fmaxf((float)c, 1.0f);
    ushort4v o; o.x = f2bf(a0 * inv); o.y = f2bf(a1 * inv);
    o.z = f2bf(a2 * inv); o.w = f2bf(a3 * inv);
    *(ushort4v*)(accb + (size_t)node * DIM + lane * 4) = o;
}

// -------------------------------- GEMM -------------------------------------
// C[m, col] = sum_k A[m,k] * W[col,k]. 128x128 tile, BK=32, 4 waves (2x2),
// each wave 64x64 via 4x4 MFMA 16x16x32 bf16. blockIdx.z batches relations.

#define BK 32

__device__ __forceinline__ void async_cp16(char* lds, const char* glb) {
    __builtin_amdgcn_global_load_lds((const __attribute__((address_space(1))) unsigned int*)glb,
                                     (__attribute__((address_space(3))) unsigned int*)lds,
                                     16, 0, 0);
}

enum { M_BF16 = 0, M_ELU = 1, M_GATE = 2, M_QKV = 3, M_RES = 4, M_GELU = 5 };

template <int MODE>
__global__ __launch_bounds__(256)
void gemm_bt(const ushortT* __restrict__ A, int lda, size_t aStrZ,
             const ushortT* __restrict__ W, int ldw, size_t wStrZ,
             int M, int K,
             float* __restrict__ outF, ushortT* __restrict__ outB, int ldo, size_t oStrZ,
             const float* __restrict__ bias,
             const ushortT* __restrict__ aux1,    // GATE: Gx (z-shared)
             const ushortT* __restrict__ aux2,    // GATE: xres (z-shared)
             const ushortT* __restrict__ resB) {  // RES: residual row (bf16)
    const size_t zi = blockIdx.z;
    A += zi * aStrZ; W += zi * wStrZ;
    if (outF) outF += zi * oStrZ;
    if (outB) outB += zi * oStrZ;

    __shared__ __align__(16) ushortT As[128 * BK];
    __shared__ __align__(16) ushortT Bs[128 * BK];
    const int tid  = threadIdx.x;
    const int wave = tid >> 6, lane = tid & 63;
    const int m0 = blockIdx.y * 128;
    const int n0 = blockIdx.x * 128;
    const int wm = (wave >> 1) * 64, wn = (wave & 1) * 64;

    floatx4 acc[4][4];
    #pragma unroll
    for (int i = 0; i < 4; ++i)
        #pragma unroll
        for (int j = 0; j < 4; ++j) acc[i][j] = (floatx4){0.f, 0.f, 0.f, 0.f};

    const int r4  = tid >> 2;            // row within 64-row chunk
    const int b16 = (tid & 3) * 16;      // byte offset in 64B row slice
    const char* Ab = (const char*)A + ((size_t)(m0 + r4) * lda) * 2 + b16;
    const char* Wb = (const char*)W + ((size_t)(n0 + r4) * ldw) * 2 + b16;
    char* Asl = (char*)As + wave * 1024; // wave-uniform LDS base
    char* Bsl = (char*)Bs + wave * 1024;

    for (int k0 = 0; k0 < K; k0 += BK) {
        async_cp16(Asl,        Ab + k0 * 2);
        async_cp16(Asl + 4096, Ab + k0 * 2 + (size_t)64 * lda * 2);
        async_cp16(Bsl,        Wb + k0 * 2);
        async_cp16(Bsl + 4096, Wb + k0 * 2 + (size_t)64 * ldw * 2);
        __syncthreads();
        const int kq = (lane >> 4) * 8;
        const int ra = wm + (lane & 15);
        const int rb = wn + (lane & 15);
        short8 af[4], bfr[4];
        #pragma unroll
        for (int i = 0; i < 4; ++i) {
            af[i]  = *(const short8*)(As + (ra + i * 16) * BK + kq);
            bfr[i] = *(const short8*)(Bs + (rb + i * 16) * BK + kq);
        }
        #pragma unroll
        for (int mi = 0; mi < 4; ++mi)
            #pragma unroll
            for (int ni = 0; ni < 4; ++ni)
                acc[mi][ni] = __builtin_amdgcn_mfma_f32_16x16x32_bf16(af[mi], bfr[ni], acc[mi][ni], 0, 0, 0);
        __syncthreads();
    }

    const int cl = lane & 15, rw = (lane >> 4) * 4;
    #pragma unroll
    for (int mi = 0; mi < 4; ++mi) {
        #pragma unroll
        for (int e = 0; e < 4; ++e) {
            const int m = m0 + wm + mi * 16 + rw + e;
            if (m >= M) continue;
            #pragma unroll
            for (int ni = 0; ni < 4; ++ni) {
                const int col = n0 + wn + ni * 16 + cl;
                float c = acc[mi][ni][e];
                if (MODE == M_BF16) {
                    outB[(size_t)m * ldo + col] = f2bf(c);
                } else if (MODE == M_ELU) {
                    c = c > 0.f ? c : (expf(c) - 1.0f);
                    outB[(size_t)m * ldo + col] = f2bf(c);
                } else if (MODE == M_GATE) {
                    float g  = bf2f(aux1[(size_t)m * 256 + col]);
                    float xr = bf2f(aux2[(size_t)m * 256 + col]);
                    float uv = bf2f(A[(size_t)m * lda + col]);
                    float a  = 1.0f / (1.0f + expf(-(c + g + bias[col])));
                    float h  = tanhf(uv) * a + xr * (1.0f - a);
                    outB[(size_t)m * ldo + col] = f2bf(h);
                } else if (MODE == M_QKV) {
                    outB[(size_t)m * ldo + col] = f2bf(c + bias[col]);
                } else if (MODE == M_RES) {
                    outF[(size_t)m * ldo + col] = c + bias[col] + bf2f(resB[(size_t)m * 256 + col]);
                } else if (MODE == M_GELU) {
                    float t = c + bias[col];
                    outB[(size_t)m * ldo + col] = f2bf(0.5f * t * (1.0f + erff(t * 0.70710678118f)));
                }
            }
        }
    }
}

// ------------------------------ attention ----------------------------------
// qk[r]: [Nc,512] bf16 (q 0..255, k 256..511). One wave per node; lanes
// 0..31 = head 0, 32..63 = head 1. Writes softmaxed A[n,2,4,4] f32.
__global__ __launch_bounds__(256)
void attn_score(const ushortT* __restrict__ qk, size_t rstride,
                float* __restrict__ Aw, int nvalid) {
    int n = blockIdx.x * 4 + (threadIdx.x >> 6);
    if (n >= nvalid) return;
    int lane = threadIdx.x & 63;
    int head = lane >> 5, hl = lane & 31;
    int d = head * 128 + hl * 4;
    float q[NREL][4], k[NREL][4];
    #pragma unroll
    for (int r = 0; r < NREL; ++r) {
        const ushortT* base = qk + r * rstride + (size_t)n * 512;
        ushort4v qv = *(const ushort4v*)(base + d);
        ushort4v kv = *(const ushort4v*)(base + 256 + d);
        q[r][0] = bf2f(qv.x); q[r][1] = bf2f(qv.y); q[r][2] = bf2f(qv.z); q[r][3] = bf2f(qv.w);
        k[r][0] = bf2f(kv.x); k[r][1] = bf2f(kv.y); k[r][2] = bf2f(kv.z); k[r][3] = bf2f(kv.w);
    }
    float s[NREL][NREL];
    #pragma unroll
    for (int qr = 0; qr < NREL; ++qr)
        #pragma unroll
        for (int kr = 0; kr < NREL; ++kr) {
            float p = q[qr][0] * k[kr][0] + q[qr][1] * k[kr][1] +
                      q[qr][2] * k[kr][2] + q[qr][3] * k[kr][3];
            #pragma unroll
            for (int off = 1; off < 32; off <<= 1) p += __shfl_xor(p, off, 32);
            s[qr][kr] = p * 0.08838834764831845f;   // 1/sqrt(128)
        }
    if (hl < 16) {
        int qr = hl >> 2, kr = hl & 3;
        float mx = fmaxf(fmaxf(s[qr][0], s[qr][1]), fmaxf(s[qr][2], s[qr][3]));
        float e0 = expf(s[qr][0] - mx), e1 = expf(s[qr][1] - mx);
        float e2 = expf(s[qr][2] - mx), e3 = expf(s[qr][3] - mx);
        float e  = expf(s[qr][kr] - mx);
        Aw[((size_t)n * 2 + head) * 16 + qr * 4 + kr] = e / (e0 + e1 + e2 + e3);
    }
}

// o[qr,n,:] = sum_kr A[n,head,qr,kr] * v[kr,n,:]
__global__ __launch_bounds__(256)
void attn_combine(const ushortT* __restrict__ v4, size_t rstride,
                  const float* __restrict__ Aw, ushortT* __restrict__ o4, int nvalid) {
    int n = blockIdx.x * 4 + (threadIdx.x >> 6);
    if (n >= nvalid) return;
    int lane = threadIdx.x & 63;
    int head = lane >> 5, d4 = lane * 4;
    float a[NREL][NREL];
    const float* ap = Aw + ((size_t)n * 2 + head) * 16;
    #pragma unroll
    for (int qr = 0; qr < NREL; ++qr)
        #pragma unroll
        for (int kr = 0; kr < NREL; ++kr) a[qr][kr] = ap[qr * 4 + kr];
    float vv[NREL][4];
    #pragma unroll
    for (int r = 0; r < NREL; ++r) {
        ushort4v t = *(const ushort4v*)(v4 + r * rstride + (size_t)n * 256 + d4);
        vv[r][0] = bf2f(t.x); vv[r][1] = bf2f(t.y); vv[r][2] = bf2f(t.z); vv[r][3] = bf2f(t.w);
    }
    #pragma unroll
    for (int qr = 0; qr < NREL; ++qr) {
        ushort4v o;
        o.x = f2bf(a[qr][0] * vv[0][0] + a[qr][1] * vv[1][0] + a[qr][2] * vv[2][0] + a[qr][3] * vv[3][0]);
        o.y = f2bf(a[qr][0] * vv[0][1] + a[qr][1] * vv[1][1] + a[qr][2] * vv[2][1] + a[qr][3] * vv[3][1]);
        o.z = f2bf(a[qr][0] * vv[0][2] + a[qr][1] * vv[1][2] + a[qr][2] * vv[2][2] + a[qr][3] * vv[3][2]);
        o.w = f2bf(a[qr][0] * vv[0][3] + a[qr][1] * vv[1][3] + a[qr][2] * vv[2][3] + a[qr][3] * vv[3][3]);
        *(ushort4v*)(o4 + qr * rstride + (size_t)n * 256 + d4) = o;
    }
}

// ------------------------------ layernorm ----------------------------------
// mode 0: write bf16 row.  mode 1: outacc[row] += 0.25 * LN(row)
__global__ __launch_bounds__(256)
void ln_rows(const float* __restrict__ z, const float* __restrict__ g, const float* __restrict__ b,
             ushortT* __restrict__ outb, float* __restrict__ outacc, int n, int mode) {
    int row = blockIdx.x * 4 + (threadIdx.x >> 6);
    if (row >= n) return;
    int lane = threadIdx.x & 63;
    const float4 v = *(const float4*)(z + (size_t)row * 256 + lane * 4);
    float s = v.x + v.y + v.z + v.w;
    #pragma unroll
    for (int off = 1; off < 64; off <<= 1) s += __shfl_xor(s, off, 64);
    float mean = s * (1.0f / 256.0f);
    float dx = v.x - mean, dy = v.y - mean, dz = v.z - mean, dw = v.w - mean;
    float qs = dx * dx + dy * dy + dz * dz + dw * dw;
    #pragma unroll
    for (int off = 1; off < 64; off <<= 1) qs += __shfl_xor(qs, off, 64);
    float rstd = rsqrtf(qs * (1.0f / 256.0f) + 1e-5f);
    int c0 = lane * 4;
    float y0 = dx * rstd * g[c0 + 0] + b[c0 + 0];
    float y1 = dy * rstd * g[c0 + 1] + b[c0 + 1];
    float y2 = dz * rstd * g[c0 + 2] + b[c0 + 2];
    float y3 = dw * rstd * g[c0 + 3] + b[c0 + 3];
    if (mode == 0) {
        ushort4v o; o.x = f2bf(y0); o.y = f2bf(y1); o.z = f2bf(y2); o.w = f2bf(y3);
        *(ushort4v*)(outb + (size_t)row * 256 + c0) = o;
    } else {
        float4* p = (float4*)(outacc + (size_t)row * 256 + c0);
        float4 cur = *p;
        cur.x += 0.25f * y0; cur.y += 0.25f * y1; cur.z += 0.25f * y2; cur.w += 0.25f * y3;
        *p = cur;
    }
}

// ------------------------------ host ---------------------------------------

extern "C" void kernel_launch(void* const* d_in, const int* in_sizes, int n_in,
                              void* d_out, int out_size, void* d_ws, size_t ws_size,
                              hipStream_t stream) {
    const float* x      = (const float*)d_in[0];
    const int*   tri    = (const int*)d_in[1];
    const float* nodeW  = (const float*)d_in[3];
    const float* triW   = (const float*)d_in[4];
    const float* resW   = (const float*)d_in[5];
    const float* gateW  = (const float*)d_in[6];
    const float* gate_b = (const float*)d_in[7];
    const float* inW    = (const float*)d_in[8];
    const float* in_b   = (const float*)d_in[9];
    const float* outW   = (const float*)d_in[10];
    const float* out_b  = (const float*)d_in[11];
    const float* ln1g   = (const float*)d_in[12];
    const float* ln1b   = (const float*)d_in[13];
    const float* lin1W  = (const float*)d_in[14];
    const float* lin1b  = (const float*)d_in[15];
    const float* lin2W  = (const float*)d_in[16];
    const float* lin2b  = (const float*)d_in[17];
    const float* ln2g   = (const float*)d_in[18];
    const float* ln2b   = (const float*)d_in[19];
    float* out = (float*)d_out;

    // ---------------- persistent workspace ----------------
    char* ws = (char*)d_ws;
    size_t off = 0;
    auto alloc = [&](size_t bytes) -> char* {
        char* p = ws + off; off += (bytes + 255) & ~(size_t)255; return p;
    };
    ushortT* accAll  = (ushortT*)alloc((size_t)NREL * NPAD * 256 * 2);  // 205 MB
    ushortT* wcomb   = (ushortT*)alloc((size_t)NREL * 65536 * 2);
    ushortT* resW_b  = (ushortT*)alloc((size_t)65536 * 2);
    ushortT* gateW_b = (ushortT*)alloc((size_t)131072 * 2);
    ushortT* inW_b   = (ushortT*)alloc((size_t)196608 * 2);
    ushortT* outW_b  = (ushortT*)alloc((size_t)65536 * 2);
    ushortT* lin1_bf = (ushortT*)alloc((size_t)131072 * 2);
    ushortT* lin2_bf = (ushortT*)alloc((size_t)131072 * 2);
    size_t persist = off;
    size_t scratch = (ws_size > persist) ? (ws_size - persist) : 0;
    char* S = ws + persist;

    // scatter-phase scratch (dead before chunk phase): CSR + meanx
    const size_t csrBytes = (size_t)NPAD * 4 * 3 + 4096 * 2 + (size_t)3 * NTRI * 4;
    const size_t mxBytes  = (size_t)NTRI * 256 * 2;                     // 77 MB
    if (scratch < csrBytes + mxBytes + 65536) return;
    int*     cntI   = (int*)(S);
    int*     ptrI   = (int*)(S + (size_t)NPAD * 4);
    int*     curI   = (int*)(S + (size_t)NPAD * 8);
    int*     bsum   = (int*)(S + (size_t)NPAD * 12);
    int*     bpre   = (int*)(S + (size_t)NPAD * 12 + 4096);
    int*     adj    = (int*)(S + (size_t)NPAD * 12 + 8192);
    ushortT* mxbf   = (ushortT*)(S + ((csrBytes + 255) & ~(size_t)255));

    // chunk scratch: 9856 B/row
    int TT = (NNODES + 127) / 128;              // 782
    int tpc = TT;
    while ((size_t)9856 * tpc * 128 > scratch && tpc > 1) tpc = (tpc + 1) / 2;
    if ((size_t)9856 * tpc * 128 > scratch) return;
    const size_t NcPad = (size_t)tpc * 128;
    const int nchunks = (TT + tpc - 1) / tpc;

    // chunk layout (byte-offset/row). Phase C aliases phase A/B regions.
    ushortT* xbf   = (ushortT*)(S);                    // A: 512
    ushortT* xres  = (ushortT*)(S + 512  * NcPad);     // A: 512 bf16
    ushortT* Gx    = (ushortT*)(S + 1024 * NcPad);     // A: 512 bf16
    ushortT* ubf4  = (ushortT*)(S + 1536 * NcPad);     // A: 4x512
    float*   zb    = (float*)  (S);                    // C: 1024 (alias xbf/xres)
    ushortT* x1    = (ushortT*)(S + 1024 * NcPad);     // C: 512 (alias Gx)
    ushortT* ffg   = (ushortT*)(S + 1536 * NcPad);     // C: 1024 (alias ubf4[0:2])
    ushortT* h4    = (ushortT*)(S + 3584 * NcPad);     // 4x512
    ushortT* qk4   = (ushortT*)(S + 5632 * NcPad);     // B: 4x1024
    ushortT* v4    = (ushortT*)(S + 5632 * NcPad);     // alias (qk dead)
    ushortT* o4    = (ushortT*)(S + 7680 * NcPad);     // alias (qk dead)
    float*   Aw    = (float*)  (S + 9728 * NcPad);     // 128

    (void)hipMemsetAsync(d_out, 0, (size_t)out_size * 4, stream);

    // ---------------- weights to bf16 + W_comb ----------------
    cvt_f32_bf16<<<64, 256, 0, stream>>>(resW,  resW_b,  65536 / 4);
    cvt_f32_bf16<<<64, 256, 0, stream>>>(gateW, gateW_b, 131072 / 4);
    cvt_f32_bf16<<<64, 256, 0, stream>>>(inW,   inW_b,   196608 / 4);
    cvt_f32_bf16<<<64, 256, 0, stream>>>(outW,  outW_b,  65536 / 4);
    cvt_f32_bf16<<<64, 256, 0, stream>>>(lin1W, lin1_bf, 131072 / 4);
    cvt_f32_bf16<<<64, 256, 0, stream>>>(lin2W, lin2_bf, 131072 / 4);
    wcomb_kernel<<<1024, 256, 0, stream>>>(nodeW, triW, wcomb);

    // ---------------- scatter phase: CSR gather per relation ----------------
    const int NB = (NNODES + 255) / 256;        // 391 scan blocks
    for (int r = 0; r < NREL; ++r) {
        const int* trir = tri + (size_t)r * 3 * NTRI;
        (void)hipMemsetAsync(cntI, 0, (size_t)NPAD * 4, stream);
        k_count<<<(3 * NTRI + 255) / 256, 256, 0, stream>>>(trir, cntI, 3 * NTRI);
        k_scan1<<<NB, 256, 0, stream>>>(cntI, ptrI, bsum, NNODES);
        k_scan2<<<1, 64, 0, stream>>>(bsum, bpre, NB);
        k_scan3<<<NB, 256, 0, stream>>>(bpre, ptrI, curI, NNODES);
        k_fill<<<(3 * NTRI + 255) / 256, 256, 0, stream>>>(trir, curI, adj, 3 * NTRI, NTRI);
        k_meanx<<<(NTRI + 3) / 4, 256, 0, stream>>>(trir, x, mxbf, NTRI);
        k_gather<<<(NNODES + 3) / 4, 256, 0, stream>>>(ptrI, cntI, adj, mxbf,
            accAll + (size_t)r * NPAD * 256, NNODES);
    }

    // ---------------- chunked main pipeline ----------------
    for (int ci = 0; ci < nchunks; ++ci) {
        const int rows0 = ci * tpc * 128;
        int mact = NNODES - rows0;
        if (mact <= 0) break;
        if (mact > tpc * 128) mact = tpc * 128;
        const int tiles = (mact + 127) / 128;
        const dim3 g2(2, tiles), g4(4, tiles);
        const dim3 g2z(2, tiles, NREL), g4z(4, tiles, NREL);
        const int nwblk = (mact + 3) / 4;
        float* outc = out + (size_t)rows0 * 256;

        cvt_f32_bf16<<<2048, 256, 0, stream>>>(x + (size_t)rows0 * 256, xbf, mact * 64);
        // xres = x @ res_W.T ; Gx = x @ gate_W[:, :D].T   (both bf16)
        gemm_bt<M_BF16><<<g2, 256, 0, stream>>>(xbf, 256, 0, resW_b, 256, 0, mact, 256,
            nullptr, xres, 256, 0, nullptr, nullptr, nullptr, nullptr);
        gemm_bt<M_BF16><<<g2, 256, 0, stream>>>(xbf, 256, 0, gateW_b, 512, 0, mact, 256,
            nullptr, Gx, 256, 0, nullptr, nullptr, nullptr, nullptr);
        // u[r] = elu(acc[r] @ W_comb[r].T)   (acc already /cnt)
        gemm_bt<M_ELU><<<g2z, 256, 0, stream>>>(
            accAll + (size_t)rows0 * 256, 256, (size_t)NPAD * 256,
            wcomb, 256, 65536, mact, 256,
            nullptr, ubf4, 256, 256 * NcPad, nullptr, nullptr, nullptr, nullptr);
        // a = sigmoid(u@gW2.T + Gx + b); h = tanh(u)*a + xres*(1-a)
        gemm_bt<M_GATE><<<g2z, 256, 0, stream>>>(
            ubf4, 256, 256 * NcPad, gateW_b + 256, 512, 0, mact, 256,
            nullptr, h4, 256, 256 * NcPad, gate_b, Gx, xres, nullptr);
        // qk[r] = h[r] @ in_W[0:512].T + b
        gemm_bt<M_QKV><<<g4z, 256, 0, stream>>>(
            h4, 256, 256 * NcPad, inW_b, 256, 0, mact, 256,
            nullptr, qk4, 512, 512 * NcPad, in_b, nullptr, nullptr, nullptr);
        attn_score<<<nwblk, 256, 0, stream>>>(qk4, 512 * NcPad, Aw, mact);
        // v[r] = h[r] @ in_W[512:768].T + b   (qk region dead)
        gemm_bt<M_QKV><<<g2z, 256, 0, stream>>>(
            h4, 256, 256 * NcPad, inW_b + 512 * 256, 256, 0, mact, 256,
            nullptr, v4, 256, 256 * NcPad, in_b + 512, nullptr, nullptr, nullptr);
        attn_combine<<<nwblk, 256, 0, stream>>>(v4, 256 * NcPad, Aw, o4, mact);

        for (int r = 0; r < NREL; ++r) {
            // z = h + o@out_W.T + out_b ; x1 = LN1(z)
            gemm_bt<M_RES><<<g2, 256, 0, stream>>>(
                o4 + (size_t)r * 256 * NcPad, 256, 0, outW_b, 256, 0, mact, 256,
                zb, nullptr, 256, 0, out_b, nullptr, nullptr, h4 + (size_t)r * 256 * NcPad);
            ln_rows<<<nwblk, 256, 0, stream>>>(zb, ln1g, ln1b, x1, nullptr, mact, 0);
            // ffg = gelu(x1 @ lin1_W.T + b)
            gemm_bt<M_GELU><<<g4, 256, 0, stream>>>(x1, 256, 0, lin1_bf, 256, 0, mact, 256,
                nullptr, ffg, 512, 0, lin1b, nullptr, nullptr, nullptr);
            // z = x1 + ffg @ lin2_W.T + b ; out += 0.25 * LN2(z)
            gemm_bt<M_RES><<<g2, 256, 0, stream>>>(ffg, 512, 0, lin2_bf, 512, 0, mact, 512,
                zb, nullptr, 256, 0, lin2b, nullptr, nullptr, x1);
            ln_rows<<<nwblk, 256, 0, stream>>>(zb, ln2g, ln2b, nullptr, outc, mact, 1);
        }
    }
}